// Round 12
// baseline (64.418 us; speedup 1.0000x reference)
//
#include <hip/hip_runtime.h>
#include <hip/hip_bf16.h>

typedef __bf16 bf16x8 __attribute__((ext_vector_type(8)));
typedef float  f32x4  __attribute__((ext_vector_type(4)));

#define LRELU_ALPHA 0.2f
#define LOG2E 1.44269504088896340736f

// native 2^x (single v_exp_f32, no OCML call)
__device__ __forceinline__ float fexp2(float x) {
#if __has_builtin(__builtin_amdgcn_exp2f)
    return __builtin_amdgcn_exp2f(x);
#else
    float r; asm("v_exp_f32 %0, %1" : "=v"(r) : "v"(x)); return r;
#endif
}

// raw barrier: drains LDS (lgkmcnt) but leaves global prefetches (vmcnt) in flight
__device__ __forceinline__ void wg_barrier() {
    asm volatile("s_waitcnt lgkmcnt(0)" ::: "memory");
    __builtin_amdgcn_s_barrier();
    asm volatile("" ::: "memory");
}

// ---------------------------------------------------------------------------
// Kernel 1: h = inp @ W (8 rows/block) -> hb (bf16), f1 = log2e*(h·a1),
// f2 = log2e*(h·a2).
// ---------------------------------------------------------------------------
__global__ __launch_bounds__(128) void gat_prep(
    const float* __restrict__ inp, const float* __restrict__ W,
    const float* __restrict__ a,
    __bf16* __restrict__ hb, float* __restrict__ f1, float* __restrict__ f2)
{
    const int r0 = blockIdx.x << 3;
    const int d  = threadIdx.x;
    __shared__ float sIn[8][128];
    __shared__ float sRed[8][4];
    #pragma unroll
    for (int r = 0; r < 8; ++r)
        sIn[r][d] = inp[(size_t)(r0 + r) * 128 + d];
    __syncthreads();

    float acc[8] = {0.f,0.f,0.f,0.f,0.f,0.f,0.f,0.f};
    #pragma unroll 4
    for (int k = 0; k < 128; ++k) {
        float wv = W[k * 128 + d];
        #pragma unroll
        for (int r = 0; r < 8; ++r) acc[r] += sIn[r][k] * wv;
    }

    const float a1 = a[d], a2 = a[128 + d];
    const int wv = d >> 6;
    #pragma unroll
    for (int r = 0; r < 8; ++r) {
        hb[(size_t)(r0 + r) * 128 + d] = (__bf16)acc[r];
        float t1 = acc[r] * a1;
        float t2 = acc[r] * a2;
        #pragma unroll
        for (int m = 1; m < 64; m <<= 1) {
            t1 += __shfl_xor(t1, m);
            t2 += __shfl_xor(t2, m);
        }
        if ((d & 63) == 0) { sRed[r][wv] = t1; sRed[r][2 + wv] = t2; }
    }
    __syncthreads();
    if (d < 8) {
        f1[r0 + d] = (sRed[d][0] + sRed[d][1]) * LOG2E;
        f2[r0 + d] = (sRed[d][2] + sRed[d][3]) * LOG2E;
    }
}

// ---------------------------------------------------------------------------
// Kernel 2: per-batch max of (prescaled) f1
// ---------------------------------------------------------------------------
__global__ __launch_bounds__(256) void gat_f1max(
    const float* __restrict__ f1, float* __restrict__ f1max)
{
    const int b = blockIdx.x;
    const int t = threadIdx.x;
    float m = -1e30f;
    for (int j = t; j < 2048; j += 256) m = fmaxf(m, f1[b * 2048 + j]);
    #pragma unroll
    for (int k = 1; k < 64; k <<= 1) m = fmaxf(m, __shfl_xor(m, k));
    __shared__ float sm[4];
    if ((t & 63) == 0) sm[t >> 6] = m;
    __syncthreads();
    if (t == 0) f1max[b] = fmaxf(fmaxf(sm[0], sm[1]), fmaxf(sm[2], sm[3]));
}

// ---------------------------------------------------------------------------
// Kernel 3: hb (bf16 [b][n][128]) -> pack: fragment-major bf16 B-operands.
// pack elem offset = (b*32 + jt)*8192 + frag*512 + lane*8, frag = D*2 + jh.
// Fragment lane(il,kg) elem e = h[jt*64 + jh*32 + kg*8 + e][D*16 + il].
// ---------------------------------------------------------------------------
__global__ __launch_bounds__(256) void gat_pack(
    const __bf16* __restrict__ hb, __bf16* __restrict__ pack)
{
    __shared__ __bf16 tile[64][72];
    const int tid = threadIdx.x;
    const int bidx = blockIdx.x;         // 512 blocks
    const int b  = bidx >> 6;
    const int tI = bidx & 63;
    const int n0 = (tI >> 1) << 6;       // j-range 64
    const int d0 = (tI & 1) << 6;        // d-range 64
    #pragma unroll
    for (int pass = 0; pass < 2; ++pass) {
        int row = (tid >> 3) + (pass << 5);
        int c   = (tid & 7) << 3;
        *(bf16x8*)&tile[row][c] =
            *(const bf16x8*)(hb + (size_t)(b * 2048 + n0 + row) * 128 + d0 + c);
    }
    __syncthreads();
    const int lane = tid & 63;
    const int il = lane & 15;
    const int kg = lane >> 4;
    #pragma unroll
    for (int pass = 0; pass < 2; ++pass) {
        const int f  = (tid >> 6) + (pass << 2);
        const int Dl = f >> 1;
        const int jh = f & 1;
        union { __bf16 e[8]; bf16x8 v; } u;
        #pragma unroll
        for (int e = 0; e < 8; ++e)
            u.e[e] = tile[(jh << 5) + (kg << 3) + e][(Dl << 4) + il];
        const size_t off = (((size_t)(b << 5) + (n0 >> 6)) << 13)
                         + ((size_t)((((d0 >> 4) + Dl) << 1) | jh) << 9)
                         + (lane << 3);
        *(bf16x8*)(pack + off) = u.v;
    }
}

// ---------------------------------------------------------------------------
// Kernel 4 v12: deep-MLP adj stream + exp-free P + ones-MFMA denominator.
// Grid 1024 (8 batch x 128 rowgroups), 256 thr (4 waves = 4 d-quarters).
// Block = 16 i-rows x 2048 j x 128 d; 16 epochs of j-tile 128.
// adj: 3-deep register pipeline, all-immediate-offset loads (96 B/thread in
// flight; issued last per iter so B-waits never drain them; lgkm-only bar).
// P = adj ? max(ai*u_j, bi*v_j) : 0   [2^max(a,b) = max(2^a,2^b)] - 5 VALU.
// Denominator = ones-B MFMA on wave dq0 (bf16-exact with numerator).
// ---------------------------------------------------------------------------
__global__ __launch_bounds__(256, 4) void gat_attn12(
    const int* __restrict__ adj, const __bf16* __restrict__ hb,
    const __bf16* __restrict__ pack, const float* __restrict__ f1g,
    const float* __restrict__ f2g, const float* __restrict__ f1maxg,
    float* __restrict__ out)
{
    const int bid = ((blockIdx.x & 7) << 7) | (blockIdx.x >> 3);  // batch<->XCD
    const int b  = bid >> 7;
    const int i0 = (bid & 127) << 4;     // 16 rows per block
    const int tid = threadIdx.x;

    __shared__ float us[2048];                    // 2^f1        (8 KB)
    __shared__ float vs[2048];                    // 2^(0.2 f1)  (8 KB)
    __shared__ alignas(16) __bf16 Ps[2][16 * 136]; // P dbuf, 272B row stride
    __shared__ float lsum[16];

    const int pi  = tid >> 4;            // P row 0..15
    const int pj4 = tid & 15;            // j-octet within tile

    // adj bases (tiles 0-7 via ajp, 8-15 via ajp8; imm offsets <= 3584+16B)
    const int* ajp  = adj + (((size_t)(b << 11) + i0 + pi) << 11) + (pj4 << 3);
    const int* ajp8 = ajp + 1024;

    // per-thread P factors
    const float fm  = f1maxg[b];
    const float f2v = f2g[(b << 11) + i0 + pi];
    const float zM  = f2v + fm;
    const float M   = fmaxf(zM, LRELU_ALPHA * zM);          // exact: p <= 1
    const float ai_ = fexp2(f2v - M);
    const float bi_ = fexp2(__builtin_fmaf(LRELU_ALPHA, f2v, -M));

    // 3-deep adj pipeline (slots = tile % 3), fully unrolled loop keeps
    // all indices static (no scratch).
    int4 As[3][2];
    As[0][0] = *(const int4*)(ajp);        As[0][1] = *(const int4*)(ajp + 4);
    As[1][0] = *(const int4*)(ajp + 128);  As[1][1] = *(const int4*)(ajp + 132);
    As[2][0] = *(const int4*)(ajp + 256);  As[2][1] = *(const int4*)(ajp + 260);

    // build us/vs: 8 j-values per thread per table
    {
        const int jb = tid << 3;
        float4 f0 = *(const float4*)&f1g[(b << 11) + jb];
        float4 f1v = *(const float4*)&f1g[(b << 11) + jb + 4];
        float4 uu0, uu1, vv0, vv1;
        uu0.x = fexp2(f0.x);  uu0.y = fexp2(f0.y);
        uu0.z = fexp2(f0.z);  uu0.w = fexp2(f0.w);
        uu1.x = fexp2(f1v.x); uu1.y = fexp2(f1v.y);
        uu1.z = fexp2(f1v.z); uu1.w = fexp2(f1v.w);
        vv0.x = fexp2(LRELU_ALPHA * f0.x);  vv0.y = fexp2(LRELU_ALPHA * f0.y);
        vv0.z = fexp2(LRELU_ALPHA * f0.z);  vv0.w = fexp2(LRELU_ALPHA * f0.w);
        vv1.x = fexp2(LRELU_ALPHA * f1v.x); vv1.y = fexp2(LRELU_ALPHA * f1v.y);
        vv1.z = fexp2(LRELU_ALPHA * f1v.z); vv1.w = fexp2(LRELU_ALPHA * f1v.w);
        *(float4*)&us[jb]     = uu0;  *(float4*)&us[jb + 4] = uu1;
        *(float4*)&vs[jb]     = vv0;  *(float4*)&vs[jb + 4] = vv1;
    }

    // wave mapping
    const int w    = tid >> 6;           // dq 0..3 -> cols dq*32..+32
    const int lane = tid & 63;
    const int il   = lane & 15;
    const int kg   = lane >> 4;
    const int dq   = w;

    f32x4 acc0 = {0,0,0,0}, acc1 = {0,0,0,0}, accd = {0,0,0,0};
    union { __bf16 e[8]; bf16x8 v; } ones;
    #pragma unroll
    for (int x = 0; x < 8; ++x) ones.e[x] = (__bf16)1.0f;
    const bf16x8 onesv = ones.v;

#define PCOMP(TT, BUF) do {                                                   \
    const int _jb = ((TT) << 7) + (pj4 << 3);                                 \
    float4 _u0 = *(const float4*)&us[_jb];                                    \
    float4 _u1 = *(const float4*)&us[_jb + 4];                                \
    float4 _v0 = *(const float4*)&vs[_jb];                                    \
    float4 _v1 = *(const float4*)&vs[_jb + 4];                                \
    int4 _aA = As[(TT) % 3][0];                                               \
    int4 _aB = As[(TT) % 3][1];                                               \
    union { __bf16 e[8]; bf16x8 v; } _pb;                                     \
    _pb.e[0] = (__bf16)((_aA.x > 0) ? fmaxf(ai_ * _u0.x, bi_ * _v0.x) : 0.f); \
    _pb.e[1] = (__bf16)((_aA.y > 0) ? fmaxf(ai_ * _u0.y, bi_ * _v0.y) : 0.f); \
    _pb.e[2] = (__bf16)((_aA.z > 0) ? fmaxf(ai_ * _u0.z, bi_ * _v0.z) : 0.f); \
    _pb.e[3] = (__bf16)((_aA.w > 0) ? fmaxf(ai_ * _u0.w, bi_ * _v0.w) : 0.f); \
    _pb.e[4] = (__bf16)((_aB.x > 0) ? fmaxf(ai_ * _u1.x, bi_ * _v1.x) : 0.f); \
    _pb.e[5] = (__bf16)((_aB.y > 0) ? fmaxf(ai_ * _u1.y, bi_ * _v1.y) : 0.f); \
    _pb.e[6] = (__bf16)((_aB.z > 0) ? fmaxf(ai_ * _u1.z, bi_ * _v1.z) : 0.f); \
    _pb.e[7] = (__bf16)((_aB.w > 0) ? fmaxf(ai_ * _u1.w, bi_ * _v1.w) : 0.f); \
    *(bf16x8*)&Ps[BUF][pi * 136 + (pj4 << 3)] = _pb.v;                        \
    if ((TT) + 3 < 16) {  /* refill slot with tile TT+3 (imm offsets) */      \
        if ((TT) + 3 < 8) {                                                   \
            As[(TT) % 3][0] = *(const int4*)(ajp + (((TT) + 3) << 7));        \
            As[(TT) % 3][1] = *(const int4*)(ajp + (((TT) + 3) << 7) + 4);    \
        } else {                                                              \
            As[(TT) % 3][0] = *(const int4*)(ajp8 + (((TT) - 5) << 7));       \
            As[(TT) % 3][1] = *(const int4*)(ajp8 + (((TT) - 5) << 7) + 4);   \
        }                                                                     \
    }                                                                         \
} while (0)

    wg_barrier();                        // us/vs ready
    PCOMP(0, 0);                         // P(0) -> Ps[0]; refill tile 3
    wg_barrier();                        // Ps[0] ready

    #pragma unroll
    for (int t = 0; t < 16; ++t) {
        // ---- B loads for tile t (issued first; consumed after PCOMP) ----
        const __bf16* bp0 = pack + (((size_t)(b << 5) + (t << 1)) << 13)
                          + (dq << 11) + (lane << 3);
        const __bf16* bp1 = bp0 + 8192;
        bf16x8 B00 = *(const bf16x8*)(bp0);          // kk0, Dl0
        bf16x8 B01 = *(const bf16x8*)(bp0 + 512);    // kk1, Dl0
        bf16x8 B02 = *(const bf16x8*)(bp0 + 1024);   // kk0, Dl1
        bf16x8 B03 = *(const bf16x8*)(bp0 + 1536);   // kk1, Dl1
        bf16x8 B10 = *(const bf16x8*)(bp1);          // kk2, Dl0
        bf16x8 B11 = *(const bf16x8*)(bp1 + 512);    // kk3, Dl0
        bf16x8 B12 = *(const bf16x8*)(bp1 + 1024);   // kk2, Dl1
        bf16x8 B13 = *(const bf16x8*)(bp1 + 1536);   // kk3, Dl1

        // ---- P(t+1) while B is in flight; adj refilled LAST (stays deep) --
        if (t < 15) PCOMP(t + 1, (t + 1) & 1);

        // ---- A-frags + MFMA from Ps[t&1] ----
        const __bf16* pr = &Ps[t & 1][0];
        const int abase = il * 136 + kg * 8;
        bf16x8 Af0 = *(const bf16x8*)(pr + abase);
        bf16x8 Af1 = *(const bf16x8*)(pr + abase + 32);
        bf16x8 Af2 = *(const bf16x8*)(pr + abase + 64);
        bf16x8 Af3 = *(const bf16x8*)(pr + abase + 96);

        acc0 = __builtin_amdgcn_mfma_f32_16x16x32_bf16(Af0, B00, acc0, 0,0,0);
        acc1 = __builtin_amdgcn_mfma_f32_16x16x32_bf16(Af0, B02, acc1, 0,0,0);
        acc0 = __builtin_amdgcn_mfma_f32_16x16x32_bf16(Af1, B01, acc0, 0,0,0);
        acc1 = __builtin_amdgcn_mfma_f32_16x16x32_bf16(Af1, B03, acc1, 0,0,0);
        acc0 = __builtin_amdgcn_mfma_f32_16x16x32_bf16(Af2, B10, acc0, 0,0,0);
        acc1 = __builtin_amdgcn_mfma_f32_16x16x32_bf16(Af2, B12, acc1, 0,0,0);
        acc0 = __builtin_amdgcn_mfma_f32_16x16x32_bf16(Af3, B11, acc0, 0,0,0);
        acc1 = __builtin_amdgcn_mfma_f32_16x16x32_bf16(Af3, B13, acc1, 0,0,0);
        if (dq == 0) {                   // denominator (bf16-exact row sums)
            accd = __builtin_amdgcn_mfma_f32_16x16x32_bf16(Af0, onesv, accd, 0,0,0);
            accd = __builtin_amdgcn_mfma_f32_16x16x32_bf16(Af1, onesv, accd, 0,0,0);
            accd = __builtin_amdgcn_mfma_f32_16x16x32_bf16(Af2, onesv, accd, 0,0,0);
            accd = __builtin_amdgcn_mfma_f32_16x16x32_bf16(Af3, onesv, accd, 0,0,0);
        }

        wg_barrier();                    // Ps[(t+1)&1] ready / reads done
    }
#undef PCOMP

    // ---- share denominators ----
    if (dq == 0 && il == 0) {
        #pragma unroll
        for (int r = 0; r < 4; ++r) lsum[(kg << 2) + r] = accd[r];
    }
    wg_barrier();

    // ---- epilogue: normalize, elu, residual ----
    #pragma unroll
    for (int r = 0; r < 4; ++r) {
        const int   row  = (kg << 2) + r;
        const float rden = 1.0f / lsum[row];
        const size_t gbase = (((size_t)(b << 11) + i0 + row) << 7) + (dq << 5) + il;
        float v, e;
        v = acc0[r] * rden; e = (v > 0.f) ? v : (fexp2(v * LOG2E) - 1.f);
        out[gbase] = e + (float)hb[gbase];
        v = acc1[r] * rden; e = (v > 0.f) ? v : (fexp2(v * LOG2E) - 1.f);
        out[gbase + 16] = e + (float)hb[gbase + 16];
    }
}

// ---------------------------------------------------------------------------
extern "C" void kernel_launch(void* const* d_in, const int* in_sizes, int n_in,
                              void* d_out, int out_size, void* d_ws, size_t ws_size,
                              hipStream_t stream)
{
    const float* inp = (const float*)d_in[0];
    const int*   adj = (const int*)d_in[1];
    const float* W   = (const float*)d_in[2];
    const float* a   = (const float*)d_in[3];
    float* out = (float*)d_out;

    // workspace layout (~8.2 MB)
    char* ws = (char*)d_ws;
    __bf16* hb    = (__bf16*)ws;                       // 4 MB
    __bf16* pack  = (__bf16*)(ws + (4 << 20));         // 4 MB
    float*  f1    = (float*)(ws + (8 << 20));          // 64 KB
    float*  f2    = (float*)(ws + (8 << 20) + 65536);
    float*  f1max = (float*)(ws + (8 << 20) + 131072);

    gat_prep<<<2048, 128, 0, stream>>>(inp, W, a, hb, f1, f2);
    gat_f1max<<<8, 256, 0, stream>>>(f1, f1max);
    gat_pack<<<512, 256, 0, stream>>>(hb, pack);
    gat_attn12<<<1024, 256, 0, stream>>>(adj, hb, pack, f1, f2, f1max, out);
}

// Round 13
// 62.620 us; speedup vs baseline: 1.0287x; 1.0287x over previous
//
#include <hip/hip_runtime.h>
#include <hip/hip_bf16.h>

typedef __bf16 bf16x8 __attribute__((ext_vector_type(8)));
typedef float  f32x4  __attribute__((ext_vector_type(4)));

#define LRELU_ALPHA 0.2f
#define LOG2E 1.44269504088896340736f

// native 2^x (single v_exp_f32, no OCML call)
__device__ __forceinline__ float fexp2(float x) {
#if __has_builtin(__builtin_amdgcn_exp2f)
    return __builtin_amdgcn_exp2f(x);
#else
    float r; asm("v_exp_f32 %0, %1" : "=v"(r) : "v"(x)); return r;
#endif
}

// raw barrier: drains LDS (lgkmcnt) but leaves global prefetches (vmcnt) in flight
__device__ __forceinline__ void wg_barrier() {
    asm volatile("s_waitcnt lgkmcnt(0)" ::: "memory");
    __builtin_amdgcn_s_barrier();
    asm volatile("" ::: "memory");
}

// ---------------------------------------------------------------------------
// Kernel 1: h = inp @ W (8 rows/block) -> hb (bf16), f1 = log2e*(h·a1),
// f2 = log2e*(h·a2).
// ---------------------------------------------------------------------------
__global__ __launch_bounds__(128) void gat_prep(
    const float* __restrict__ inp, const float* __restrict__ W,
    const float* __restrict__ a,
    __bf16* __restrict__ hb, float* __restrict__ f1, float* __restrict__ f2)
{
    const int r0 = blockIdx.x << 3;
    const int d  = threadIdx.x;
    __shared__ float sIn[8][128];
    __shared__ float sRed[8][4];
    #pragma unroll
    for (int r = 0; r < 8; ++r)
        sIn[r][d] = inp[(size_t)(r0 + r) * 128 + d];
    __syncthreads();

    float acc[8] = {0.f,0.f,0.f,0.f,0.f,0.f,0.f,0.f};
    #pragma unroll 4
    for (int k = 0; k < 128; ++k) {
        float wv = W[k * 128 + d];
        #pragma unroll
        for (int r = 0; r < 8; ++r) acc[r] += sIn[r][k] * wv;
    }

    const float a1 = a[d], a2 = a[128 + d];
    const int wv = d >> 6;
    #pragma unroll
    for (int r = 0; r < 8; ++r) {
        hb[(size_t)(r0 + r) * 128 + d] = (__bf16)acc[r];
        float t1 = acc[r] * a1;
        float t2 = acc[r] * a2;
        #pragma unroll
        for (int m = 1; m < 64; m <<= 1) {
            t1 += __shfl_xor(t1, m);
            t2 += __shfl_xor(t2, m);
        }
        if ((d & 63) == 0) { sRed[r][wv] = t1; sRed[r][2 + wv] = t2; }
    }
    __syncthreads();
    if (d < 8) {
        f1[r0 + d] = (sRed[d][0] + sRed[d][1]) * LOG2E;
        f2[r0 + d] = (sRed[d][2] + sRed[d][3]) * LOG2E;
    }
}

// ---------------------------------------------------------------------------
// Kernel 2: per-batch max of (prescaled) f1
// ---------------------------------------------------------------------------
__global__ __launch_bounds__(256) void gat_f1max(
    const float* __restrict__ f1, float* __restrict__ f1max)
{
    const int b = blockIdx.x;
    const int t = threadIdx.x;
    float m = -1e30f;
    for (int j = t; j < 2048; j += 256) m = fmaxf(m, f1[b * 2048 + j]);
    #pragma unroll
    for (int k = 1; k < 64; k <<= 1) m = fmaxf(m, __shfl_xor(m, k));
    __shared__ float sm[4];
    if ((t & 63) == 0) sm[t >> 6] = m;
    __syncthreads();
    if (t == 0) f1max[b] = fmaxf(fmaxf(sm[0], sm[1]), fmaxf(sm[2], sm[3]));
}

// ---------------------------------------------------------------------------
// Kernel 3: hb (bf16 [b][n][128]) -> pack: fragment-major bf16 B-operands.
// pack elem offset = (b*32 + jt)*8192 + frag*512 + lane*8, frag = D*2 + jh.
// Fragment lane(il,kg) elem e = h[jt*64 + jh*32 + kg*8 + e][D*16 + il].
// ---------------------------------------------------------------------------
__global__ __launch_bounds__(256) void gat_pack(
    const __bf16* __restrict__ hb, __bf16* __restrict__ pack)
{
    __shared__ __bf16 tile[64][72];
    const int tid = threadIdx.x;
    const int bidx = blockIdx.x;         // 512 blocks
    const int b  = bidx >> 6;
    const int tI = bidx & 63;
    const int n0 = (tI >> 1) << 6;       // j-range 64
    const int d0 = (tI & 1) << 6;        // d-range 64
    #pragma unroll
    for (int pass = 0; pass < 2; ++pass) {
        int row = (tid >> 3) + (pass << 5);
        int c   = (tid & 7) << 3;
        *(bf16x8*)&tile[row][c] =
            *(const bf16x8*)(hb + (size_t)(b * 2048 + n0 + row) * 128 + d0 + c);
    }
    __syncthreads();
    const int lane = tid & 63;
    const int il = lane & 15;
    const int kg = lane >> 4;
    #pragma unroll
    for (int pass = 0; pass < 2; ++pass) {
        const int f  = (tid >> 6) + (pass << 2);
        const int Dl = f >> 1;
        const int jh = f & 1;
        union { __bf16 e[8]; bf16x8 v; } u;
        #pragma unroll
        for (int e = 0; e < 8; ++e)
            u.e[e] = tile[(jh << 5) + (kg << 3) + e][(Dl << 4) + il];
        const size_t off = (((size_t)(b << 5) + (n0 >> 6)) << 13)
                         + ((size_t)((((d0 >> 4) + Dl) << 1) | jh) << 9)
                         + (lane << 3);
        *(bf16x8*)(pack + off) = u.v;
    }
}

// ---------------------------------------------------------------------------
// Kernel 4 v13: panel-amortized fused attention partials.
// Grid 512 = 8 batch x 16 rowgroups(128 rows) x 4 j-quarters; 512 thr (8 waves).
// Wave w owns rows w*16..+16 and ALL 128 d; P computed ONCE per lane in regs
// (its own A-frag, exp-free); B tile (32j x 128d = 8KB) staged to LDS once per
// iter and shared by all 8 waves (L3 B-traffic 512MB -> 64MB). Denominator via
// ones-MFMA. One lgkm-only barrier/iter; adj 2-deep, stage 1-deep prefetch.
// Partials: jq=0 -> out (f32); jq=1..3 -> pO (bf16); den -> pD.
// ---------------------------------------------------------------------------
__global__ __launch_bounds__(512, 4) void gat_attn13(
    const int* __restrict__ adj, const __bf16* __restrict__ pack,
    const float* __restrict__ f1g, const float* __restrict__ f2g,
    const float* __restrict__ f1maxg,
    float* __restrict__ out, __bf16* __restrict__ pO, float* __restrict__ pD)
{
    const int bid = ((blockIdx.x & 7) << 6) | (blockIdx.x >> 3);  // batch<->XCD
    const int b  = bid >> 6;
    const int rg = (bid >> 2) & 15;
    const int jq = bid & 3;
    const int i0 = rg << 7;              // 128 rows per block
    const int jb = jq << 9;              // 512-j quarter
    const int tid = threadIdx.x;

    __shared__ float us[512];            // 2^f1 slice       (2 KB)
    __shared__ float vs[512];            // 2^(0.2 f1) slice (2 KB)
    __shared__ alignas(16) __bf16 Bs[2][4096];   // B tile dbuf (2 x 8 KB)

    const int w    = tid >> 6;           // wave 0..7 -> rows w*16..+16
    const int lane = tid & 63;
    const int il   = lane & 15;
    const int kg   = lane >> 4;

    // j-side tables (this quarter only)
    if (tid < 128) {
        float4 fv = *(const float4*)&f1g[(b << 11) + jb + (tid << 2)];
        float4 uu, vv;
        uu.x = fexp2(fv.x); uu.y = fexp2(fv.y);
        uu.z = fexp2(fv.z); uu.w = fexp2(fv.w);
        vv.x = fexp2(LRELU_ALPHA * fv.x); vv.y = fexp2(LRELU_ALPHA * fv.y);
        vv.z = fexp2(LRELU_ALPHA * fv.z); vv.w = fexp2(LRELU_ALPHA * fv.w);
        *(float4*)&us[tid << 2] = uu;
        *(float4*)&vs[tid << 2] = vv;
    }

    // per-lane P factors (rows of wave w)
    const int row  = i0 + (w << 4) + il;
    const float fm  = f1maxg[b];
    const float f2v = f2g[(b << 11) + row];
    const float zM  = f2v + fm;
    const float M   = fmaxf(zM, LRELU_ALPHA * zM);        // exact: p <= 1
    const float ai_ = fexp2(f2v - M);
    const float bi_ = fexp2(__builtin_fmaf(LRELU_ALPHA, f2v, -M));

    // adj base: lane covers j = jb + t*32 + kg*8 .. +8
    const int* ap = adj + (((size_t)(b << 11) + row) << 11) + jb + (kg << 3);

    // stage base: wave w stages fragment D=w; frag offset(t) =
    // ((t>>1)<<13) + ((t&1)<<9) relative to (b,jq) base.
    const __bf16* pkB = pack + (((size_t)(b << 5) + (jq << 3)) << 13)
                      + ((w << 1) << 9) + (lane << 3);

    f32x4 acc[8];
    #pragma unroll
    for (int D = 0; D < 8; ++D) acc[D] = (f32x4){0.f, 0.f, 0.f, 0.f};
    f32x4 accd = {0.f, 0.f, 0.f, 0.f};
    union { __bf16 e[8]; bf16x8 v; } ones;
    #pragma unroll
    for (int x = 0; x < 8; ++x) ones.e[x] = (__bf16)1.0f;
    const bf16x8 onesv = ones.v;

    // ---- prologue: B(0) staged; B(1) + adj(0),adj(1) in flight ----
    int4 adjx[2], adjy[2];
    int4 sg = *(const int4*)(pkB);                 // B(0)
    adjx[0] = *(const int4*)(ap);
    adjy[0] = *(const int4*)(ap + 4);
    adjx[1] = *(const int4*)(ap + 32);
    adjy[1] = *(const int4*)(ap + 36);
    *(int4*)&Bs[0][(w << 9) + (lane << 3)] = sg;   // vmcnt(sg) auto
    sg = *(const int4*)(pkB + 512);                // B(1): off ((1>>1)<<13)+(1<<9)

    wg_barrier();                                  // us/vs + Bs[0] ready

    #pragma unroll
    for (int t = 0; t < 16; ++t) {
        const int cb = t & 1;

        // ---- B-frag reads (conflict-free: lane*16B contiguous) ----
        bf16x8 Bf[8];
        #pragma unroll
        for (int D = 0; D < 8; ++D)
            Bf[D] = *(const bf16x8*)&Bs[cb][(D << 9) + (lane << 3)];

        // ---- P(t): 8 exp-free values (own A-frag) ----
        const int4 ax = adjx[t & 1];
        const int4 ay = adjy[t & 1];
        const float4 u0 = *(const float4*)&us[t * 32 + (kg << 3)];
        const float4 u1 = *(const float4*)&us[t * 32 + (kg << 3) + 4];
        const float4 v0 = *(const float4*)&vs[t * 32 + (kg << 3)];
        const float4 v1 = *(const float4*)&vs[t * 32 + (kg << 3) + 4];
        union { __bf16 e[8]; bf16x8 v; } pa;
        pa.e[0] = (ax.x > 0) ? (__bf16)fmaxf(ai_ * u0.x, bi_ * v0.x) : (__bf16)0.f;
        pa.e[1] = (ax.y > 0) ? (__bf16)fmaxf(ai_ * u0.y, bi_ * v0.y) : (__bf16)0.f;
        pa.e[2] = (ax.z > 0) ? (__bf16)fmaxf(ai_ * u0.z, bi_ * v0.z) : (__bf16)0.f;
        pa.e[3] = (ax.w > 0) ? (__bf16)fmaxf(ai_ * u0.w, bi_ * v0.w) : (__bf16)0.f;
        pa.e[4] = (ay.x > 0) ? (__bf16)fmaxf(ai_ * u1.x, bi_ * v1.x) : (__bf16)0.f;
        pa.e[5] = (ay.y > 0) ? (__bf16)fmaxf(ai_ * u1.y, bi_ * v1.y) : (__bf16)0.f;
        pa.e[6] = (ay.z > 0) ? (__bf16)fmaxf(ai_ * u1.z, bi_ * v1.z) : (__bf16)0.f;
        pa.e[7] = (ay.w > 0) ? (__bf16)fmaxf(ai_ * u1.w, bi_ * v1.w) : (__bf16)0.f;

        // ---- refill adj slot with tile t+2 (imm offsets; stays in flight) --
        if (t + 2 < 16) {
            adjx[t & 1] = *(const int4*)(ap + (t + 2) * 32);
            adjy[t & 1] = *(const int4*)(ap + (t + 2) * 32 + 4);
        }

        // ---- 9 MFMAs ----
        #pragma unroll
        for (int D = 0; D < 8; ++D)
            acc[D] = __builtin_amdgcn_mfma_f32_16x16x32_bf16(pa.v, Bf[D], acc[D], 0, 0, 0);
        accd = __builtin_amdgcn_mfma_f32_16x16x32_bf16(pa.v, onesv, accd, 0, 0, 0);

        // ---- stage B(t+1) -> other buffer; issue B(t+2) ----
        if (t < 15) {
            *(int4*)&Bs[cb ^ 1][(w << 9) + (lane << 3)] = sg;  // vmcnt leaves adj in flight
            if (t < 14)
                sg = *(const int4*)(pkB + (((t + 2) >> 1) << 13) + (((t + 2) & 1) << 9));
            wg_barrier();
        }
    }

    // ---- write partials: C row = kg*4+r, col = il (+ D*16) ----
    const int rowg = (b << 11) + i0 + (w << 4) + (kg << 2);
    if (jq == 0) {
        #pragma unroll
        for (int r = 0; r < 4; ++r) {
            const size_t base = (((size_t)rowg + r) << 7) + il;
            #pragma unroll
            for (int D = 0; D < 8; ++D)
                out[base + (D << 4)] = acc[D][r];
        }
    } else {
        __bf16* po = pO + ((size_t)(jq - 1) << 21);
        #pragma unroll
        for (int r = 0; r < 4; ++r) {
            const size_t base = (((size_t)rowg + r) << 7) + il;
            #pragma unroll
            for (int D = 0; D < 8; ++D)
                po[base + (D << 4)] = (__bf16)acc[D][r];
        }
    }
    if (il == 0) {
        #pragma unroll
        for (int r = 0; r < 4; ++r)
            pD[(jq << 14) + rowg + r] = accd[r];
    }
}

// ---------------------------------------------------------------------------
// Kernel 5: combine 4 j-quarter partials, normalize, elu, residual.
// io aliases out (jq=0 partial): read-before-write per element, same thread.
// ---------------------------------------------------------------------------
__global__ __launch_bounds__(256) void gat_combine(
    float* io, const __bf16* __restrict__ pO,
    const float* __restrict__ pD, const __bf16* __restrict__ hb)
{
    const int idx = blockIdx.x * 256 + threadIdx.x;    // 0..262143
    const size_t base = (size_t)idx << 3;
    const int rowAll = idx >> 4;                       // 16 threads per 128-row
    const float den = pD[rowAll] + pD[16384 + rowAll]
                    + pD[32768 + rowAll] + pD[49152 + rowAll];
    const float rden = 1.0f / den;
    float4 o0a = *(const float4*)(io + base);
    float4 o0b = *(const float4*)(io + base + 4);
    bf16x8 p1 = *(const bf16x8*)(pO + base);
    bf16x8 p2 = *(const bf16x8*)(pO + (1u << 21) + base);
    bf16x8 p3 = *(const bf16x8*)(pO + (2u << 21) + base);
    bf16x8 hv = *(const bf16x8*)(hb + base);
    float res[8];
    #pragma unroll
    for (int e = 0; e < 8; ++e) {
        float o = ((e < 4) ? ((const float*)&o0a)[e] : ((const float*)&o0b)[e - 4])
                + (float)p1[e] + (float)p2[e] + (float)p3[e];
        float v  = o * rden;
        float el = (v > 0.f) ? v : (fexp2(v * LOG2E) - 1.f);
        res[e] = el + (float)hv[e];
    }
    *(float4*)(io + base)     = (float4){res[0], res[1], res[2], res[3]};
    *(float4*)(io + base + 4) = (float4){res[4], res[5], res[6], res[7]};
}

// ---------------------------------------------------------------------------
extern "C" void kernel_launch(void* const* d_in, const int* in_sizes, int n_in,
                              void* d_out, int out_size, void* d_ws, size_t ws_size,
                              hipStream_t stream)
{
    const float* inp = (const float*)d_in[0];
    const int*   adj = (const int*)d_in[1];
    const float* W   = (const float*)d_in[2];
    const float* a   = (const float*)d_in[3];
    float* out = (float*)d_out;

    // workspace layout (~20.5 MB)
    char* ws = (char*)d_ws;
    __bf16* hb    = (__bf16*)ws;                          // 4 MB
    __bf16* pack  = (__bf16*)(ws + (4 << 20));            // 4 MB
    __bf16* pO    = (__bf16*)(ws + (8 << 20));            // 12 MB (3 bf16 partials)
    float*  pD    = (float*)(ws + (20 << 20));            // 256 KB (4 x 16384)
    float*  f1    = (float*)(ws + (20 << 20) + 262144);   // 64 KB
    float*  f2    = (float*)(ws + (20 << 20) + 262144 + 65536);
    float*  f1max = (float*)(ws + (20 << 20) + 262144 + 131072);

    gat_prep<<<2048, 128, 0, stream>>>(inp, W, a, hb, f1, f2);
    gat_f1max<<<8, 256, 0, stream>>>(f1, f1max);
    gat_pack<<<512, 256, 0, stream>>>(hb, pack);
    gat_attn13<<<512, 512, 0, stream>>>(adj, pack, f1, f2, f1max, out, pO, pD);
    gat_combine<<<1024, 256, 0, stream>>>(out, pO, pD, hb);
}